// Round 4
// baseline (531.330 us; speedup 1.0000x reference)
//
#include <hip/hip_runtime.h>

// Problem constants (match reference)
#define OUT_F 4096   // M
#define IN_F  4096   // K
#define NCOLS 8192   // N

#define GM OUT_F
#define GK IN_F
#define GN NCOLS

typedef __attribute__((ext_vector_type(8))) short short8;
typedef __attribute__((ext_vector_type(4))) float f32x4;

// ---------------------------------------------------------------------------
// helpers
// ---------------------------------------------------------------------------
__device__ inline unsigned short f2bf(float f) {
    union { float f; unsigned u; } c; c.f = f;
    unsigned u = c.u;
    u += 0x7fffu + ((u >> 16) & 1u);   // round-to-nearest-even
    return (unsigned short)(u >> 16);
}

__device__ inline void gll16(const void* g, void* l) {
    __builtin_amdgcn_global_load_lds(
        (const __attribute__((address_space(1))) unsigned int*)g,
        (__attribute__((address_space(3))) unsigned int*)l, 16, 0, 0);
}

// ---------------------------------------------------------------------------
// Densify path
// ---------------------------------------------------------------------------
__global__ void scatter_dense(const int* __restrict__ rows, const int* __restrict__ cols,
                              const float* __restrict__ vals, float* __restrict__ W, int nnz) {
    int i = blockIdx.x * blockDim.x + threadIdx.x;
    if (i < nnz) atomicAdd(&W[(size_t)rows[i] * IN_F + cols[i]], vals[i]);
}

__global__ void convert_w(const float* __restrict__ Wf, unsigned short* __restrict__ Wb) {
    int i = blockIdx.x * blockDim.x + threadIdx.x;  // over elems/4
    float4 v = ((const float4*)Wf)[i];
    ushort4 o;
    o.x = f2bf(v.x); o.y = f2bf(v.y); o.z = f2bf(v.z); o.w = f2bf(v.w);
    ((ushort4*)Wb)[i] = o;
}

// x [IN_F][NCOLS] f32 -> xT [NCOLS][IN_F] bf16, 64x64 tiles via LDS
__global__ __launch_bounds__(256) void transpose_x(const float* __restrict__ x,
                                                   unsigned short* __restrict__ xT) {
    __shared__ float tile[64][65];
    const int k0 = blockIdx.x * 64;   // x row block (K dim)
    const int n0 = blockIdx.y * 64;   // x col block (N dim)
    const int t = threadIdx.x;
    const int c4 = (t & 15) * 4;
    const int r0 = t >> 4;            // 0..15
    for (int p = 0; p < 4; ++p) {
        int r = r0 + p * 16;
        float4 v = *(const float4*)&x[(size_t)(k0 + r) * NCOLS + n0 + c4];
        tile[r][c4 + 0] = v.x; tile[r][c4 + 1] = v.y;
        tile[r][c4 + 2] = v.z; tile[r][c4 + 3] = v.w;
    }
    __syncthreads();
    const int n  = t >> 2;            // 0..63
    const int ks = (t & 3) * 16;      // 0,16,32,48
    unsigned w[8];
    for (int m = 0; m < 8; ++m) {
        unsigned short lo = f2bf(tile[ks + 2 * m + 0][n]);
        unsigned short hi = f2bf(tile[ks + 2 * m + 1][n]);
        w[m] = (unsigned)lo | ((unsigned)hi << 16);
    }
    uint4* dst = (uint4*)&xT[(size_t)(n0 + n) * GK + k0 + ks];
    dst[0] = make_uint4(w[0], w[1], w[2], w[3]);
    dst[1] = make_uint4(w[4], w[5], w[6], w[7]);
}

// ---------------------------------------------------------------------------
// GEMM: C[GM][GN] f32 = A(bf16 [GM][GK]) * B, with B given as BT bf16 [GN][GK].
// R4: same rolling 1-barrier pipeline as R3, but with the m201-proven sync idiom:
//   __builtin_amdgcn_s_barrier()  (waitcnt pass special-cases it: NO counter flush,
//   but it IS a memory-op ordering fence) + BARE asm("s_waitcnt vmcnt(N)") with no
//   "memory" clobber. R3 used asm(...:::"memory") for both, which makes the
//   waitcnt pass conservatively flush vmcnt(0)/lgkmcnt(0) before the asm ->
//   full drain every phase -> serial drain+compute (2342 cyc/phase vs 1242 floor).
//
//   512 thr = 8 waves (2M x 4N), per-wave output 128x64.
//   LDS = 4 rotating slots, each = A(256rows x 32k) + B(256rows x 32k) bf16 = 32 KiB.
//   Phase p (K=32, 32 MFMA/wave):
//     s_waitcnt vmcnt(4)   // retires stage of slot p+1 (issued at phase p-2)
//     s_barrier            // cross-wave residency + WAR fence
//     ds_read af2 (slot p, rows 64..127) + bf/af1 (slot p+1)   // 12 ds_read_b128
//     stage slot p+3 (4 x global_load_lds w16)
//     setprio(1); 32 MFMA (af1 x bf -> acc[0..3], af2 x bf -> acc[4..7]); setprio(0)
//   Compiler's own lgkm tracking covers the ds_read->MFMA deps (af/bf read one
//   phase ahead; af2 covered by the first 16-MFMA burst). vmcnt never drains
//   below 4 (2 slots of stages permanently in flight).
//   Hazards: slots {p, p+1, p+3} distinct mod 4; stage@p overwrites slot p-1,
//   whose last reads were consumed by MFMA@p-1 operand-waits (precede barrier@p).
//   Swizzle (unchanged, conflict-free): k-block j of row r at slot j^((r>>1)&3),
//   staged via pre-swizzled global source (rule #21), read with same involution.
// ---------------------------------------------------------------------------
__global__ __launch_bounds__(512, 2) void gemm256(const unsigned short* __restrict__ A,
                                                  const unsigned short* __restrict__ BT,
                                                  float* __restrict__ C) {
    __shared__ unsigned short lds[65536];   // 128 KiB: A slots [0,32768), B slots [32768,65536)

    const int tid  = threadIdx.x;
    const int wave = tid >> 6;
    const int lane = tid & 63;

    // XCD-aware bijective swizzle (nwg = 512, 512 % 8 == 0)
    const int wg  = blockIdx.y * 32 + blockIdx.x;
    const int swz = (wg & 7) * 64 + (wg >> 3);
    const int m0  = (swz >> 5) * 256;
    const int n0  = (swz & 31) * 256;

    const int wm = wave >> 2;          // 0..1  (M half of tile)
    const int wn = wave & 3;           // 0..3  (N quarter of tile)

    // staging mapping: chunk c = q*512 + tid; row r = c>>2 (0..255), slot s = c&3.
    // lane fetches global k-block s^((r>>1)&3) so linear LDS slot s holds swizzled data.
    const int r0s  = tid >> 2;                              // 0..127 (q=0), +128 for q=1
    const int swz0 = ((tid & 3) ^ ((r0s >> 1) & 3)) << 3;   // elems
    const unsigned short* pA0 = A  + (size_t)(m0 + r0s) * GK + swz0;
    const unsigned short* pA1 = pA0 + (size_t)128 * GK;
    const unsigned short* pB0 = BT + (size_t)(n0 + r0s) * GK + swz0;
    const unsigned short* pB1 = pB0 + (size_t)128 * GK;

    // fragment mapping for 16x16x32: row = 16*frag + frow, k-block = lane>>4
    const int frow  = lane & 15;
    const int ajb   = ((lane >> 4) ^ ((frow >> 1) & 3)) << 3;   // swizzled 8-elem block
    const int abase = ((wm << 7) + frow) * 32 + ajb;            // A region elem offset
    const int bbase = ((wn << 6) + frow) * 32 + ajb;            // B region elem offset

    f32x4 acc[8][4] = {};

    // stage slot s_ with data for phase q_ (global k = 32*q_)
#define STAGE(q_, s_) do {                                              \
        const int ko_ = (((q_) & 127) << 5);                            \
        gll16(pA0 + ko_, &lds[(s_) * 8192 + (wave << 9)]);              \
        gll16(pA1 + ko_, &lds[(s_) * 8192 + 4096 + (wave << 9)]);       \
        gll16(pB0 + ko_, &lds[32768 + (s_) * 8192 + (wave << 9)]);      \
        gll16(pB1 + ko_, &lds[32768 + (s_) * 8192 + 4096 + (wave << 9)]); \
    } while (0)

    // prologue: slots 0,1,2 staged; slot 0 resident; phase-0 frags in flight
    STAGE(0, 0); STAGE(1, 1); STAGE(2, 2);
    asm volatile("s_waitcnt vmcnt(8)");                // slot 0 resident (bare: no flush)
    __builtin_amdgcn_s_barrier();

    short8 bfX[4], afX[4], bfY[4], afY[4];
    {
        const unsigned short* Ar0 = &lds[0];
        const unsigned short* Br0 = &lds[32768];
#pragma unroll
        for (int nj = 0; nj < 4; ++nj) bfX[nj] = *(const short8*)&Br0[bbase + nj * 512];
#pragma unroll
        for (int mi = 0; mi < 4; ++mi) afX[mi] = *(const short8*)&Ar0[abase + mi * 512];
    }

// one phase: e_ = p&3 (compile-time), bfC/afC = current set, bfN/afN = next set
#define PHASE(e_, bfC, afC, bfN, afN, jj) do {                                  \
        asm volatile("s_waitcnt vmcnt(4)");                                     \
        __builtin_amdgcn_s_barrier();                                           \
        const unsigned short* ArC = &lds[(e_) * 8192];                          \
        const unsigned short* ArN = &lds[(((e_) + 1) & 3) * 8192];              \
        const unsigned short* BrN = &lds[32768 + (((e_) + 1) & 3) * 8192];      \
        short8 af2[4];                                                          \
        _Pragma("unroll")                                                       \
        for (int mi = 0; mi < 4; ++mi)                                          \
            af2[mi] = *(const short8*)&ArC[abase + (4 + mi) * 512];             \
        _Pragma("unroll")                                                       \
        for (int nj = 0; nj < 4; ++nj)                                          \
            bfN[nj] = *(const short8*)&BrN[bbase + nj * 512];                   \
        _Pragma("unroll")                                                       \
        for (int mi = 0; mi < 4; ++mi)                                          \
            afN[mi] = *(const short8*)&ArN[abase + mi * 512];                   \
        STAGE(4 * (jj) + (e_) + 3, ((e_) + 3) & 3);                             \
        __builtin_amdgcn_s_setprio(1);                                          \
        _Pragma("unroll")                                                       \
        for (int mi = 0; mi < 4; ++mi)                                          \
            _Pragma("unroll")                                                   \
            for (int nj = 0; nj < 4; ++nj)                                      \
                acc[mi][nj] = __builtin_amdgcn_mfma_f32_16x16x32_bf16(          \
                    afC[mi], bfC[nj], acc[mi][nj], 0, 0, 0);                    \
        _Pragma("unroll")                                                       \
        for (int mi = 0; mi < 4; ++mi)                                          \
            _Pragma("unroll")                                                   \
            for (int nj = 0; nj < 4; ++nj)                                      \
                acc[4 + mi][nj] = __builtin_amdgcn_mfma_f32_16x16x32_bf16(      \
                    af2[mi], bfC[nj], acc[4 + mi][nj], 0, 0, 0);                \
        __builtin_amdgcn_s_setprio(0);                                          \
    } while (0)

#pragma unroll 1
    for (int j = 0; j < GK / 128; ++j) {   // 32 iters x 4 phases = 128 phases (K=32 each)
        PHASE(0, bfX, afX, bfY, afY, j);
        PHASE(1, bfY, afY, bfX, afX, j);
        PHASE(2, bfX, afX, bfY, afY, j);
        PHASE(3, bfY, afY, bfX, afX, j);
    }
#undef PHASE
#undef STAGE

    // epilogue: C/D layout col=lane&15, row=(lane>>4)*4+reg
    for (int mi = 0; mi < 8; ++mi) {
        const int r0w = m0 + wm * 128 + mi * 16 + (lane >> 4) * 4;
        for (int nj = 0; nj < 4; ++nj) {
            const int cc = n0 + wn * 64 + nj * 16 + frow;
            for (int r = 0; r < 4; ++r)
                C[(size_t)(r0w + r) * GN + cc] = acc[mi][nj][r];
        }
    }
}

// ---------------------------------------------------------------------------
// Fallback SpMM path (round-1 kernel) if workspace is too small for densify
// ---------------------------------------------------------------------------
#define WS_COUNTS  0
#define WS_OFFSETS 4097
#define WS_CURSOR  8194
#define WS_HEADER  12290

__global__ void hist_kernel(const int* __restrict__ rows, int* __restrict__ counts, int nnz) {
    int i = blockIdx.x * blockDim.x + threadIdx.x;
    if (i < nnz) atomicAdd(&counts[rows[i]], 1);
}

__global__ void scan_kernel(const int* __restrict__ counts, int* __restrict__ offsets) {
    __shared__ int lsum[256];
    int t = threadIdx.x;
    int base = t * 16;
    int local[16];
    int s = 0;
    for (int i = 0; i < 16; ++i) { local[i] = counts[base + i]; s += local[i]; }
    lsum[t] = s;
    __syncthreads();
    if (t == 0) {
        int acc = 0;
        for (int i = 0; i < 256; ++i) { int v = lsum[i]; lsum[i] = acc; acc += v; }
        offsets[OUT_F] = acc;
    }
    __syncthreads();
    int acc = lsum[t];
    for (int i = 0; i < 16; ++i) { offsets[base + i] = acc; acc += local[i]; }
}

__global__ void scatter_kernel(const int* __restrict__ rows, const int* __restrict__ cols,
                               const float* __restrict__ vals,
                               const int* __restrict__ offsets, int* __restrict__ cursor,
                               int* __restrict__ cols_s, float* __restrict__ vals_s, int nnz) {
    int i = blockIdx.x * blockDim.x + threadIdx.x;
    if (i < nnz) {
        int r = rows[i];
        int pos = offsets[r] + atomicAdd(&cursor[r], 1);
        cols_s[pos] = cols[i];
        vals_s[pos] = vals[i];
    }
}

__global__ __launch_bounds__(256) void spmm_kernel(const int* __restrict__ offsets,
                                                   const int* __restrict__ cols_s,
                                                   const float* __restrict__ vals_s,
                                                   const float* __restrict__ x,
                                                   float* __restrict__ out) {
    const int row  = blockIdx.x;
    const int col0 = blockIdx.y * 1024 + threadIdx.x * 4;
    const int k0 = offsets[row];
    const int k1 = offsets[row + 1];
    float4 acc = make_float4(0.f, 0.f, 0.f, 0.f);
    for (int k = k0; k < k1; ++k) {
        const int   c = cols_s[k];
        const float v = vals_s[k];
        const float4 xv = *reinterpret_cast<const float4*>(x + (size_t)c * NCOLS + col0);
        acc.x += v * xv.x;
        acc.y += v * xv.y;
        acc.z += v * xv.z;
        acc.w += v * xv.w;
    }
    *reinterpret_cast<float4*>(out + (size_t)row * NCOLS + col0) = acc;
}

// ---------------------------------------------------------------------------
extern "C" void kernel_launch(void* const* d_in, const int* in_sizes, int n_in,
                              void* d_out, int out_size, void* d_ws, size_t ws_size,
                              hipStream_t stream) {
    const int*   rows = (const int*)d_in[0];
    const int*   cols = (const int*)d_in[1];
    const float* vals = (const float*)d_in[2];
    const float* x    = (const float*)d_in[3];
    float*       out  = (float*)d_out;
    const int nnz = in_sizes[0];

    const size_t WF_BYTES = (size_t)GM * GK * 4;   // 64 MB fp32 W (later reused for xT)
    const size_t WB_BYTES = (size_t)GM * GK * 2;   // 32 MB bf16 W
    const size_t NEED = WF_BYTES + WB_BYTES;       // 96 MB

    if (ws_size >= NEED) {
        float*          Wf = (float*)d_ws;
        unsigned short* Wb = (unsigned short*)((char*)d_ws + WF_BYTES);
        unsigned short* xT = (unsigned short*)d_ws;  // reuses Wf region after convert_w

        hipMemsetAsync(Wf, 0, WF_BYTES, stream);
        scatter_dense<<<(nnz + 255) / 256, 256, 0, stream>>>(rows, cols, vals, Wf, nnz);
        convert_w<<<(GM * GK / 4) / 256, 256, 0, stream>>>(Wf, Wb);
        // Wf is dead now; overwrite its region with xT
        dim3 tg(GK / 64, GN / 64);
        transpose_x<<<tg, 256, 0, stream>>>(x, xT);
        dim3 gg(GN / 256, GM / 256);
        gemm256<<<gg, 512, 0, stream>>>(Wb, xT, out);
    } else {
        // fallback: CSR SpMM (round-1 path)
        int*   ws_i    = (int*)d_ws;
        int*   counts  = ws_i + WS_COUNTS;
        int*   offsets = ws_i + WS_OFFSETS;
        int*   cursor  = ws_i + WS_CURSOR;
        int*   cols_s  = ws_i + WS_HEADER;
        float* vals_s  = (float*)(ws_i + WS_HEADER + nnz);

        hipMemsetAsync(d_ws, 0, (size_t)WS_HEADER * sizeof(int), stream);
        const int nblk = (nnz + 255) / 256;
        hist_kernel<<<nblk, 256, 0, stream>>>(rows, counts, nnz);
        scan_kernel<<<1, 256, 0, stream>>>(counts, offsets);
        scatter_kernel<<<nblk, 256, 0, stream>>>(rows, cols, vals, offsets, cursor,
                                                 cols_s, vals_s, nnz);
        dim3 grid(OUT_F, NCOLS / 1024);
        spmm_kernel<<<grid, 256, 0, stream>>>(offsets, cols_s, vals_s, x, out);
    }
}

// Round 5
// 504.562 us; speedup vs baseline: 1.0531x; 1.0531x over previous
//
#include <hip/hip_runtime.h>

// Problem constants (match reference)
#define OUT_F 4096   // M
#define IN_F  4096   // K
#define NCOLS 8192   // N

#define GM OUT_F
#define GK IN_F
#define GN NCOLS

typedef __attribute__((ext_vector_type(8))) short short8;
typedef __attribute__((ext_vector_type(4))) float f32x4;

// ---------------------------------------------------------------------------
// helpers
// ---------------------------------------------------------------------------
__device__ inline unsigned short f2bf(float f) {
    union { float f; unsigned u; } c; c.f = f;
    unsigned u = c.u;
    u += 0x7fffu + ((u >> 16) & 1u);   // round-to-nearest-even
    return (unsigned short)(u >> 16);
}

__device__ inline void gll16(const void* g, void* l) {
    __builtin_amdgcn_global_load_lds(
        (const __attribute__((address_space(1))) unsigned int*)g,
        (__attribute__((address_space(3))) unsigned int*)l, 16, 0, 0);
}

// ---------------------------------------------------------------------------
// Densify path
// ---------------------------------------------------------------------------
__global__ void scatter_dense(const int* __restrict__ rows, const int* __restrict__ cols,
                              const float* __restrict__ vals, float* __restrict__ W, int nnz) {
    int i = blockIdx.x * blockDim.x + threadIdx.x;
    if (i < nnz) atomicAdd(&W[(size_t)rows[i] * IN_F + cols[i]], vals[i]);
}

__global__ void convert_w(const float* __restrict__ Wf, unsigned short* __restrict__ Wb) {
    int i = blockIdx.x * blockDim.x + threadIdx.x;  // over elems/4
    float4 v = ((const float4*)Wf)[i];
    ushort4 o;
    o.x = f2bf(v.x); o.y = f2bf(v.y); o.z = f2bf(v.z); o.w = f2bf(v.w);
    ((ushort4*)Wb)[i] = o;
}

// x [IN_F][NCOLS] f32 -> xT [NCOLS][IN_F] bf16, 64x64 tiles via LDS
__global__ __launch_bounds__(256) void transpose_x(const float* __restrict__ x,
                                                   unsigned short* __restrict__ xT) {
    __shared__ float tile[64][65];
    const int k0 = blockIdx.x * 64;   // x row block (K dim)
    const int n0 = blockIdx.y * 64;   // x col block (N dim)
    const int t = threadIdx.x;
    const int c4 = (t & 15) * 4;
    const int r0 = t >> 4;            // 0..15
    for (int p = 0; p < 4; ++p) {
        int r = r0 + p * 16;
        float4 v = *(const float4*)&x[(size_t)(k0 + r) * NCOLS + n0 + c4];
        tile[r][c4 + 0] = v.x; tile[r][c4 + 1] = v.y;
        tile[r][c4 + 2] = v.z; tile[r][c4 + 3] = v.w;
    }
    __syncthreads();
    const int n  = t >> 2;            // 0..63
    const int ks = (t & 3) * 16;      // 0,16,32,48
    unsigned w[8];
    for (int m = 0; m < 8; ++m) {
        unsigned short lo = f2bf(tile[ks + 2 * m + 0][n]);
        unsigned short hi = f2bf(tile[ks + 2 * m + 1][n]);
        w[m] = (unsigned)lo | ((unsigned)hi << 16);
    }
    uint4* dst = (uint4*)&xT[(size_t)(n0 + n) * GK + k0 + ks];
    dst[0] = make_uint4(w[0], w[1], w[2], w[3]);
    dst[1] = make_uint4(w[4], w[5], w[6], w[7]);
}

// ---------------------------------------------------------------------------
// GEMM: C[GM][GN] f32 = A(bf16 [GM][GK]) * B, with B given as BT bf16 [GN][GK].
// R5: literal m201 8-phase shape.
//   256x256 tile, 512 thr = 8 waves (2M x 4N), per-wave out 128x64, BK=64.
//   LDS 128 KiB = 2 buf x {A,B} x 2 half-tiles (128 rows x 64 k bf16 = 16 KB).
//   K-tile t lives in buf t&1; 4 phases per K-tile (quadrant = M-half H x K-half s):
//     P1 (H0,s0): ds_read bf(s0)[4]+af[4] | stage A-halves of t+1 (4 gll) | bar |
//                 setprio 16 MFMA setprio | bar
//     P2 (H1,s0): ds_read af[4]           | stage B-halves of t+1 (4 gll) | bar | 16 MFMA | bar
//     P3 (H0,s1): ds_read bf(s1)[4]+af[4] | bar | 16 MFMA | bar
//     P4 (H1,s1): ds_read af[4] | s_waitcnt vmcnt(0) | bar | 16 MFMA | bar
//   The vmcnt(0) drain waits only on stages issued >=2 phases earlier (~1700+ cyc
//   > 900 cyc HBM latency) -> near-zero stall; it makes tile t+1 resident for the
//   next K-tile's P1 reads. Reads are phase-local (no long-lived frag arrays ->
//   register pressure drops off the 256 cap, so the scheduler can't sink them),
//   and pinned before a barrier so they can't move past the MFMA cluster.
//   WAR safe: stage@t.P1 writes buf(1-c) whose last reads (t-1.P4) are lgkm-drained
//   before that wave's MFMA, which precedes the closing barrier stage waits on.
//   LDS layout per half-tile: 128 rows x 128 B (8 x 16B slots); logical k-block j
//   of row r at slot j^(r&7) (the proven 0-conflict gemm_bt swizzle, rule #21:
//   pre-swizzled global source + same involution on ds_read).
//   wg swizzle: XCD-aware AND N-banded so the resident half-grid touches only
//   16 N-tiles (A 33MB + B 33MB fits LLC) -> cut the 625 MB HBM over-fetch.
// ---------------------------------------------------------------------------
__global__ __launch_bounds__(512, 2) void gemm256(const unsigned short* __restrict__ A,
                                                  const unsigned short* __restrict__ BT,
                                                  float* __restrict__ C) {
    __shared__ unsigned short lds[65536];   // 128 KiB

    const int tid  = threadIdx.x;
    const int wave = tid >> 6;
    const int lane = tid & 63;

    // XCD-aware, N-banded bijective swizzle (nwg = 512)
    const int wg   = blockIdx.y * 32 + blockIdx.x;
    const int xcd  = wg & 7;
    const int ii   = wg >> 3;                       // 0..63
    const int m0   = ((((ii & 7) << 1) | (xcd & 1))) << 8;        // 16 M-tiles
    const int n0   = ((((ii >> 3) << 2) | ((xcd >> 1) & 3))) << 8; // 32 N-tiles, banded by 4
    const int wm = wave >> 2;          // 0..1  (M half of tile)
    const int wn = wave & 3;           // 0..3  (N quarter of tile)

    // ---- staging (per-thread): chunk = q*512+tid; row = chunk>>3 (0..127), blk = tid&7
    // fetch global k-block blk^(row&7) so linear LDS slot blk holds swizzled data.
    // (row&7 is q-invariant since q flips row by 64.)
    const int sb = ((tid & 7) ^ ((tid >> 3) & 7)) << 3;   // src elem offset in 64k row
    const unsigned short* pAs = A  + (size_t)(m0 + (tid >> 3)) * GK + sb;
    const unsigned short* pBs = BT + (size_t)(n0 + (tid >> 3)) * GK + sb;

    // ---- fragment mapping (16x16x32): frow = lane&15, k-block jhi = lane>>4
    // half-tile row r = H*64 + mi*16 + frow (A) / (wn&1)*64 + nj*16 + frow (B);
    // logical block jl = s*4+jhi at slot jl^(r&7), r&7 == frow&7.
    const int frow = lane & 15;
    const int jhi  = lane >> 4;
    const int so0  = ((jhi ^ (frow & 7)) << 3) + frow * 64;         // s=0
    const int so1  = (((4 | jhi) ^ (frow & 7)) << 3) + frow * 64;   // s=1
    const int ab   = (wn & 1) << 12;   // B row-block offset (64 rows * 64 elems)

    f32x4 acc[8][4] = {};

    // LDS region (elems): ((c*2+op)*2+h) * 8192
#define REGION(c_, op_, h_) ((((((c_) << 1) | (op_)) << 1) | (h_)) << 13)

    // stage half-tile (op,h) of K-tile T into buf c_ (2 gll/thread)
#define STG(c_, op_, h_, T_) do {                                               \
        const unsigned short* _p = ((op_) ? pBs : pAs)                          \
                                   + (size_t)((h_) * 128) * GK + ((T_) << 6);   \
        gll16(_p,                  &lds[REGION(c_, op_, h_) + (wave << 9)]);    \
        gll16(_p + (size_t)64 * GK, &lds[REGION(c_, op_, h_) + 4096 + (wave << 9)]); \
    } while (0)

#define MFMA16(H_)                                                              \
        __builtin_amdgcn_s_setprio(1);                                          \
        _Pragma("unroll")                                                       \
        for (int mi = 0; mi < 4; ++mi)                                          \
            _Pragma("unroll")                                                   \
            for (int nj = 0; nj < 4; ++nj)                                      \
                acc[(H_) * 4 + mi][nj] = __builtin_amdgcn_mfma_f32_16x16x32_bf16( \
                    af[mi], bf[nj], acc[(H_) * 4 + mi][nj], 0, 0, 0);           \
        __builtin_amdgcn_s_setprio(0);

    // one K-tile: buf c_, staging K-tile T_ into buf cn_
#define KTILE(c_, cn_, T_) do {                                                 \
        const int Ab = (((c_) << 2) | wm) << 13;                                \
        const int Bb = (((((c_) << 1) | 1) << 1) | (wn >> 1)) << 13;            \
        short8 bf[4], af[4];                                                    \
        /* P1: H0 s0 */                                                         \
        _Pragma("unroll")                                                       \
        for (int nj = 0; nj < 4; ++nj)                                          \
            bf[nj] = *(const short8*)&lds[Bb + ab + nj * 1024 + so0];           \
        _Pragma("unroll")                                                       \
        for (int mi = 0; mi < 4; ++mi)                                          \
            af[mi] = *(const short8*)&lds[Ab + mi * 1024 + so0];                \
        STG(cn_, 0, 0, T_); STG(cn_, 0, 1, T_);                                 \
        __builtin_amdgcn_s_barrier();                                           \
        MFMA16(0)                                                               \
        __builtin_amdgcn_s_barrier();                                           \
        /* P2: H1 s0 */                                                         \
        _Pragma("unroll")                                                       \
        for (int mi = 0; mi < 4; ++mi)                                          \
            af[mi] = *(const short8*)&lds[Ab + 4096 + mi * 1024 + so0];         \
        STG(cn_, 1, 0, T_); STG(cn_, 1, 1, T_);                                 \
        __builtin_amdgcn_s_barrier();                                           \
        MFMA16(1)                                                               \
        __builtin_amdgcn_s_barrier();                                           \
        /* P3: H0 s1 */                                                         \
        _Pragma("unroll")                                                       \
        for (int nj = 0; nj < 4; ++nj)                                          \
            bf[nj] = *(const short8*)&lds[Bb + ab + nj * 1024 + so1];           \
        _Pragma("unroll")                                                       \
        for (int mi = 0; mi < 4; ++mi)                                          \
            af[mi] = *(const short8*)&lds[Ab + mi * 1024 + so1];                \
        __builtin_amdgcn_s_barrier();                                           \
        MFMA16(0)                                                               \
        __builtin_amdgcn_s_barrier();                                           \
        /* P4: H1 s1 */                                                         \
        _Pragma("unroll")                                                       \
        for (int mi = 0; mi < 4; ++mi)                                          \
            af[mi] = *(const short8*)&lds[Ab + 4096 + mi * 1024 + so1];         \
        asm volatile("s_waitcnt vmcnt(0)");                                     \
        __builtin_amdgcn_s_barrier();                                           \
        MFMA16(1)                                                               \
        __builtin_amdgcn_s_barrier();                                           \
    } while (0)

    // prologue: K-tile 0 -> buf0, drain, sync
    STG(0, 0, 0, 0); STG(0, 0, 1, 0); STG(0, 1, 0, 0); STG(0, 1, 1, 0);
    asm volatile("s_waitcnt vmcnt(0)");
    __builtin_amdgcn_s_barrier();

#pragma unroll 1
    for (int t2 = 0; t2 < GK / 128; ++t2) {   // 32 iters x 2 K-tiles (8 phases/iter)
        KTILE(0, 1, 2 * t2 + 1);
        KTILE(1, 0, (2 * t2 + 2) & 63);       // wrap at end: staged, never read
    }
#undef KTILE
#undef MFMA16
#undef STG
#undef REGION

    // epilogue: C/D layout col=lane&15, row=(lane>>4)*4+reg
    for (int mi = 0; mi < 8; ++mi) {
        const int r0w = m0 + wm * 128 + mi * 16 + (lane >> 4) * 4;
        for (int nj = 0; nj < 4; ++nj) {
            const int cc = n0 + wn * 64 + nj * 16 + frow;
            for (int r = 0; r < 4; ++r)
                C[(size_t)(r0w + r) * GN + cc] = acc[mi][nj][r];
        }
    }
}

// ---------------------------------------------------------------------------
// Fallback SpMM path (round-1 kernel) if workspace is too small for densify
// ---------------------------------------------------------------------------
#define WS_COUNTS  0
#define WS_OFFSETS 4097
#define WS_CURSOR  8194
#define WS_HEADER  12290

__global__ void hist_kernel(const int* __restrict__ rows, int* __restrict__ counts, int nnz) {
    int i = blockIdx.x * blockDim.x + threadIdx.x;
    if (i < nnz) atomicAdd(&counts[rows[i]], 1);
}

__global__ void scan_kernel(const int* __restrict__ counts, int* __restrict__ offsets) {
    __shared__ int lsum[256];
    int t = threadIdx.x;
    int base = t * 16;
    int local[16];
    int s = 0;
    for (int i = 0; i < 16; ++i) { local[i] = counts[base + i]; s += local[i]; }
    lsum[t] = s;
    __syncthreads();
    if (t == 0) {
        int acc = 0;
        for (int i = 0; i < 256; ++i) { int v = lsum[i]; lsum[i] = acc; acc += v; }
        offsets[OUT_F] = acc;
    }
    __syncthreads();
    int acc = lsum[t];
    for (int i = 0; i < 16; ++i) { offsets[base + i] = acc; acc += local[i]; }
}

__global__ void scatter_kernel(const int* __restrict__ rows, const int* __restrict__ cols,
                               const float* __restrict__ vals,
                               const int* __restrict__ offsets, int* __restrict__ cursor,
                               int* __restrict__ cols_s, float* __restrict__ vals_s, int nnz) {
    int i = blockIdx.x * blockDim.x + threadIdx.x;
    if (i < nnz) {
        int r = rows[i];
        int pos = offsets[r] + atomicAdd(&cursor[r], 1);
        cols_s[pos] = cols[i];
        vals_s[pos] = vals[i];
    }
}

__global__ __launch_bounds__(256) void spmm_kernel(const int* __restrict__ offsets,
                                                   const int* __restrict__ cols_s,
                                                   const float* __restrict__ vals_s,
                                                   const float* __restrict__ x,
                                                   float* __restrict__ out) {
    const int row  = blockIdx.x;
    const int col0 = blockIdx.y * 1024 + threadIdx.x * 4;
    const int k0 = offsets[row];
    const int k1 = offsets[row + 1];
    float4 acc = make_float4(0.f, 0.f, 0.f, 0.f);
    for (int k = k0; k < k1; ++k) {
        const int   c = cols_s[k];
        const float v = vals_s[k];
        const float4 xv = *reinterpret_cast<const float4*>(x + (size_t)c * NCOLS + col0);
        acc.x += v * xv.x;
        acc.y += v * xv.y;
        acc.z += v * xv.z;
        acc.w += v * xv.w;
    }
    *reinterpret_cast<float4*>(out + (size_t)row * NCOLS + col0) = acc;
}

// ---------------------------------------------------------------------------
extern "C" void kernel_launch(void* const* d_in, const int* in_sizes, int n_in,
                              void* d_out, int out_size, void* d_ws, size_t ws_size,
                              hipStream_t stream) {
    const int*   rows = (const int*)d_in[0];
    const int*   cols = (const int*)d_in[1];
    const float* vals = (const float*)d_in[2];
    const float* x    = (const float*)d_in[3];
    float*       out  = (float*)d_out;
    const int nnz = in_sizes[0];

    const size_t WF_BYTES = (size_t)GM * GK * 4;   // 64 MB fp32 W (later reused for xT)
    const size_t WB_BYTES = (size_t)GM * GK * 2;   // 32 MB bf16 W
    const size_t NEED = WF_BYTES + WB_BYTES;       // 96 MB

    if (ws_size >= NEED) {
        float*          Wf = (float*)d_ws;
        unsigned short* Wb = (unsigned short*)((char*)d_ws + WF_BYTES);
        unsigned short* xT = (unsigned short*)d_ws;  // reuses Wf region after convert_w

        hipMemsetAsync(Wf, 0, WF_BYTES, stream);
        scatter_dense<<<(nnz + 255) / 256, 256, 0, stream>>>(rows, cols, vals, Wf, nnz);
        convert_w<<<(GM * GK / 4) / 256, 256, 0, stream>>>(Wf, Wb);
        // Wf is dead now; overwrite its region with xT
        dim3 tg(GK / 64, GN / 64);
        transpose_x<<<tg, 256, 0, stream>>>(x, xT);
        dim3 gg(GN / 256, GM / 256);
        gemm256<<<gg, 512, 0, stream>>>(Wb, xT, out);
    } else {
        // fallback: CSR SpMM (round-1 path)
        int*   ws_i    = (int*)d_ws;
        int*   counts  = ws_i + WS_COUNTS;
        int*   offsets = ws_i + WS_OFFSETS;
        int*   cursor  = ws_i + WS_CURSOR;
        int*   cols_s  = ws_i + WS_HEADER;
        float* vals_s  = (float*)(ws_i + WS_HEADER + nnz);

        hipMemsetAsync(d_ws, 0, (size_t)WS_HEADER * sizeof(int), stream);
        const int nblk = (nnz + 255) / 256;
        hist_kernel<<<nblk, 256, 0, stream>>>(rows, counts, nnz);
        scan_kernel<<<1, 256, 0, stream>>>(counts, offsets);
        scatter_kernel<<<nblk, 256, 0, stream>>>(rows, cols, vals, offsets, cursor,
                                                 cols_s, vals_s, nnz);
        dim3 grid(OUT_F, NCOLS / 1024);
        spmm_kernel<<<grid, 256, 0, stream>>>(offsets, cols_s, vals_s, x, out);
    }
}

// Round 6
// 501.731 us; speedup vs baseline: 1.0590x; 1.0056x over previous
//
#include <hip/hip_runtime.h>

// Problem constants (match reference)
#define OUT_F 4096   // M
#define IN_F  4096   // K
#define NCOLS 8192   // N

#define GM OUT_F
#define GK IN_F
#define GN NCOLS

typedef __attribute__((ext_vector_type(8))) short short8;
typedef __attribute__((ext_vector_type(4))) float f32x4;

// ---------------------------------------------------------------------------
// helpers
// ---------------------------------------------------------------------------
__device__ inline unsigned short f2bf(float f) {
    union { float f; unsigned u; } c; c.f = f;
    unsigned u = c.u;
    u += 0x7fffu + ((u >> 16) & 1u);   // round-to-nearest-even
    return (unsigned short)(u >> 16);
}

__device__ inline void gll16(const void* g, void* l) {
    __builtin_amdgcn_global_load_lds(
        (const __attribute__((address_space(1))) unsigned int*)g,
        (__attribute__((address_space(3))) unsigned int*)l, 16, 0, 0);
}

// ---------------------------------------------------------------------------
// Densify path
// ---------------------------------------------------------------------------
__global__ void scatter_dense(const int* __restrict__ rows, const int* __restrict__ cols,
                              const float* __restrict__ vals, float* __restrict__ W, int nnz) {
    int i = blockIdx.x * blockDim.x + threadIdx.x;
    if (i < nnz) atomicAdd(&W[(size_t)rows[i] * IN_F + cols[i]], vals[i]);
}

__global__ void convert_w(const float* __restrict__ Wf, unsigned short* __restrict__ Wb) {
    int i = blockIdx.x * blockDim.x + threadIdx.x;  // over elems/4
    float4 v = ((const float4*)Wf)[i];
    ushort4 o;
    o.x = f2bf(v.x); o.y = f2bf(v.y); o.z = f2bf(v.z); o.w = f2bf(v.w);
    ((ushort4*)Wb)[i] = o;
}

// x [IN_F][NCOLS] f32 -> xT [NCOLS][IN_F] bf16, 64x64 tiles via LDS
__global__ __launch_bounds__(256) void transpose_x(const float* __restrict__ x,
                                                   unsigned short* __restrict__ xT) {
    __shared__ float tile[64][65];
    const int k0 = blockIdx.x * 64;   // x row block (K dim)
    const int n0 = blockIdx.y * 64;   // x col block (N dim)
    const int t = threadIdx.x;
    const int c4 = (t & 15) * 4;
    const int r0 = t >> 4;            // 0..15
    for (int p = 0; p < 4; ++p) {
        int r = r0 + p * 16;
        float4 v = *(const float4*)&x[(size_t)(k0 + r) * NCOLS + n0 + c4];
        tile[r][c4 + 0] = v.x; tile[r][c4 + 1] = v.y;
        tile[r][c4 + 2] = v.z; tile[r][c4 + 3] = v.w;
    }
    __syncthreads();
    const int n  = t >> 2;            // 0..63
    const int ks = (t & 3) * 16;      // 0,16,32,48
    unsigned w[8];
    for (int m = 0; m < 8; ++m) {
        unsigned short lo = f2bf(tile[ks + 2 * m + 0][n]);
        unsigned short hi = f2bf(tile[ks + 2 * m + 1][n]);
        w[m] = (unsigned)lo | ((unsigned)hi << 16);
    }
    uint4* dst = (uint4*)&xT[(size_t)(n0 + n) * GK + k0 + ks];
    dst[0] = make_uint4(w[0], w[1], w[2], w[3]);
    dst[1] = make_uint4(w[4], w[5], w[6], w[7]);
}

// ---------------------------------------------------------------------------
// GEMM: C[GM][GN] f32 = A(bf16 [GM][GK]) * B, with B given as BT bf16 [GN][GK].
// R6: 4-slot rotation + phase-local reads + COUNTED vmcnt (m218 lever).
//   256x256 tile, 512 thr = 8 waves (2M x 4N), per-wave out 128x64.
//   LDS = 4 rotating slots of 32 KB: slot s = { A 256rows x 32k | B 256rows x 32k }.
//   One phase per BK=32 K-tile t (slot s = t&3):
//     ds_read bf[4] + af[4] + af2[4] from slot s      (12 ds_read_b128, phase-local)
//     STAGE tile t+3 -> slot (t+3)&3                  (4 gll16)
//     s_waitcnt vmcnt(8)    // counted: retires stages from t-2 and older ONLY
//     s_barrier
//     setprio(1); 32 MFMA (af x bf -> acc[0..3], af2 x bf -> acc[4..7]); setprio(0)
//     s_barrier
//   Ledger: wait@p guarantees tile p+1 (staged @p-2, ~2 phases ~= 1600cyc old >
//   900cyc HBM latency -> near-zero stall) resident before p+1's reads; barrier
//   seals cross-wave. Never drains below 8 outstanding (2 tiles in flight).
//   WAR: stage@p overwrites slot of tile p-1, whose reads were consumed into
//   MFMA operands before p-1's closing barrier. Slots {p, p+3} distinct mod 4.
//   32 MFMA per barrier-pair (vs R5's 16) halves barrier crossings.
//   Swizzle (R2-verified, 0 conflicts): 64B row = 4x16B slots; logical k-block j
//   of row r at slot j^((r>>1)&3); pre-swizzled global source (rule #21), same
//   involution on fragment reads. All row terms ==0 mod 8 so (r>>1)&3 == (frow>>1)&3.
//   wg swizzle: XCD-aware + N-banded (R5-verified: FETCH 625->199 MB).
// ---------------------------------------------------------------------------
__global__ __launch_bounds__(512, 2) void gemm256(const unsigned short* __restrict__ A,
                                                  const unsigned short* __restrict__ BT,
                                                  float* __restrict__ C) {
    __shared__ unsigned short lds[65536];   // 128 KiB = 4 slots x 16384 elems

    const int tid  = threadIdx.x;
    const int wave = tid >> 6;
    const int lane = tid & 63;

    // XCD-aware, N-banded bijective swizzle (nwg = 512)
    const int wg   = blockIdx.y * 32 + blockIdx.x;
    const int xcd  = wg & 7;
    const int ii   = wg >> 3;                       // 0..63
    const int m0   = ((((ii & 7) << 1) | (xcd & 1))) << 8;         // 16 M-tiles
    const int n0   = ((((ii >> 3) << 2) | ((xcd >> 1) & 3))) << 8; // 32 N-tiles, banded by 4
    const int wm = wave >> 2;          // 0..1  (M half of tile)
    const int wn = wave & 3;           // 0..3  (N quarter of tile)

    // ---- staging: chunk c = q*512 + tid; row = c>>2 (0..127 q=0, +128 q=1), slot = c&3.
    // fetch global k-block (c&3)^((row>>1)&3) so linear LDS slot holds swizzled data.
    // ((row>>1)&3 is q-invariant: +128 rows -> +64 in >>1 space == 0 mod 4.)
    const int r0s  = tid >> 2;                              // 0..127
    const int swz0 = ((tid & 3) ^ ((r0s >> 1) & 3)) << 3;   // elems
    const unsigned short* pA0 = A  + (size_t)(m0 + r0s) * GK + swz0;
    const unsigned short* pA1 = pA0 + (size_t)128 * GK;
    const unsigned short* pB0 = BT + (size_t)(n0 + r0s) * GK + swz0;
    const unsigned short* pB1 = pB0 + (size_t)128 * GK;

    // ---- fragment mapping (16x16x32): frow = lane&15, k-block jhi = lane>>4
    // A row r = wm*128 + H*64 + mi*16 + frow; B row r = wn*64 + nj*16 + frow.
    // All non-frow terms == 0 mod 8 -> (r>>1)&3 == (frow>>1)&3.
    const int frow  = lane & 15;
    const int ajb   = ((lane >> 4) ^ ((frow >> 1) & 3)) << 3;   // swizzled 8-elem block
    const int abase = (((wm << 7) + frow) << 5) + ajb;          // A elem offset in slot
    const int bbase = (((wn << 6) + frow) << 5) + 8192 + ajb;   // B elem offset in slot

    f32x4 acc[8][4] = {};

    // stage K-tile T_ into slot s_ (4 gll16/thread; dest wave-uniform + lane*16)
#define STAGE(T_, s_) do {                                              \
        const int ko_ = ((T_) & 127) << 5;                              \
        gll16(pA0 + ko_, &lds[(s_) * 16384 + (wave << 9)]);             \
        gll16(pA1 + ko_, &lds[(s_) * 16384 + 4096 + (wave << 9)]);      \
        gll16(pB0 + ko_, &lds[(s_) * 16384 + 8192 + (wave << 9)]);      \
        gll16(pB1 + ko_, &lds[(s_) * 16384 + 12288 + (wave << 9)]);     \
    } while (0)

    // prologue: tiles 0,1,2 -> slots 0,1,2; tile 0 resident (12 out, wait to 8)
    STAGE(0, 0); STAGE(1, 1); STAGE(2, 2);
    asm volatile("s_waitcnt vmcnt(8)");
    __builtin_amdgcn_s_barrier();

// one phase: e_ = t&3 compile-time; reads slot e_, stages tile 4*jj+e_+3
#define PHASE(e_, jj) do {                                                      \
        const unsigned short* Ar = &lds[(e_) * 16384];                          \
        short8 bf[4], af[4], af2[4];                                            \
        _Pragma("unroll")                                                       \
        for (int nj = 0; nj < 4; ++nj)                                          \
            bf[nj] = *(const short8*)&Ar[bbase + nj * 512];                     \
        _Pragma("unroll")                                                       \
        for (int mi = 0; mi < 4; ++mi)                                          \
            af[mi] = *(const short8*)&Ar[abase + mi * 512];                     \
        _Pragma("unroll")                                                       \
        for (int mi = 0; mi < 4; ++mi)                                          \
            af2[mi] = *(const short8*)&Ar[abase + 2048 + mi * 512];             \
        STAGE(4 * (jj) + (e_) + 3, ((e_) + 3) & 3);                             \
        asm volatile("s_waitcnt vmcnt(8)");                                     \
        __builtin_amdgcn_s_barrier();                                           \
        __builtin_amdgcn_s_setprio(1);                                          \
        _Pragma("unroll")                                                       \
        for (int mi = 0; mi < 4; ++mi)                                          \
            _Pragma("unroll")                                                   \
            for (int nj = 0; nj < 4; ++nj)                                      \
                acc[mi][nj] = __builtin_amdgcn_mfma_f32_16x16x32_bf16(          \
                    af[mi], bf[nj], acc[mi][nj], 0, 0, 0);                      \
        _Pragma("unroll")                                                       \
        for (int mi = 0; mi < 4; ++mi)                                          \
            _Pragma("unroll")                                                   \
            for (int nj = 0; nj < 4; ++nj)                                      \
                acc[4 + mi][nj] = __builtin_amdgcn_mfma_f32_16x16x32_bf16(      \
                    af2[mi], bf[nj], acc[4 + mi][nj], 0, 0, 0);                 \
        __builtin_amdgcn_s_setprio(0);                                          \
        __builtin_amdgcn_s_barrier();                                           \
    } while (0)

#pragma unroll 1
    for (int j = 0; j < GK / 128; ++j) {   // 32 iters x 4 phases (BK=32 each)
        PHASE(0, j);
        PHASE(1, j);
        PHASE(2, j);
        PHASE(3, j);
    }
#undef PHASE
#undef STAGE

    // epilogue: C/D layout col=lane&15, row=(lane>>4)*4+reg
    for (int mi = 0; mi < 8; ++mi) {
        const int r0w = m0 + wm * 128 + mi * 16 + (lane >> 4) * 4;
        for (int nj = 0; nj < 4; ++nj) {
            const int cc = n0 + wn * 64 + nj * 16 + frow;
            for (int r = 0; r < 4; ++r)
                C[(size_t)(r0w + r) * GN + cc] = acc[mi][nj][r];
        }
    }
}

// ---------------------------------------------------------------------------
// Fallback SpMM path (round-1 kernel) if workspace is too small for densify
// ---------------------------------------------------------------------------
#define WS_COUNTS  0
#define WS_OFFSETS 4097
#define WS_CURSOR  8194
#define WS_HEADER  12290

__global__ void hist_kernel(const int* __restrict__ rows, int* __restrict__ counts, int nnz) {
    int i = blockIdx.x * blockDim.x + threadIdx.x;
    if (i < nnz) atomicAdd(&counts[rows[i]], 1);
}

__global__ void scan_kernel(const int* __restrict__ counts, int* __restrict__ offsets) {
    __shared__ int lsum[256];
    int t = threadIdx.x;
    int base = t * 16;
    int local[16];
    int s = 0;
    for (int i = 0; i < 16; ++i) { local[i] = counts[base + i]; s += local[i]; }
    lsum[t] = s;
    __syncthreads();
    if (t == 0) {
        int acc = 0;
        for (int i = 0; i < 256; ++i) { int v = lsum[i]; lsum[i] = acc; acc += v; }
        offsets[OUT_F] = acc;
    }
    __syncthreads();
    int acc = lsum[t];
    for (int i = 0; i < 16; ++i) { offsets[base + i] = acc; acc += local[i]; }
}

__global__ void scatter_kernel(const int* __restrict__ rows, const int* __restrict__ cols,
                               const float* __restrict__ vals,
                               const int* __restrict__ offsets, int* __restrict__ cursor,
                               int* __restrict__ cols_s, float* __restrict__ vals_s, int nnz) {
    int i = blockIdx.x * blockDim.x + threadIdx.x;
    if (i < nnz) {
        int r = rows[i];
        int pos = offsets[r] + atomicAdd(&cursor[r], 1);
        cols_s[pos] = cols[i];
        vals_s[pos] = vals[i];
    }
}

__global__ __launch_bounds__(256) void spmm_kernel(const int* __restrict__ offsets,
                                                   const int* __restrict__ cols_s,
                                                   const float* __restrict__ vals_s,
                                                   const float* __restrict__ x,
                                                   float* __restrict__ out) {
    const int row  = blockIdx.x;
    const int col0 = blockIdx.y * 1024 + threadIdx.x * 4;
    const int k0 = offsets[row];
    const int k1 = offsets[row + 1];
    float4 acc = make_float4(0.f, 0.f, 0.f, 0.f);
    for (int k = k0; k < k1; ++k) {
        const int   c = cols_s[k];
        const float v = vals_s[k];
        const float4 xv = *reinterpret_cast<const float4*>(x + (size_t)c * NCOLS + col0);
        acc.x += v * xv.x;
        acc.y += v * xv.y;
        acc.z += v * xv.z;
        acc.w += v * xv.w;
    }
    *reinterpret_cast<float4*>(out + (size_t)row * NCOLS + col0) = acc;
}

// ---------------------------------------------------------------------------
extern "C" void kernel_launch(void* const* d_in, const int* in_sizes, int n_in,
                              void* d_out, int out_size, void* d_ws, size_t ws_size,
                              hipStream_t stream) {
    const int*   rows = (const int*)d_in[0];
    const int*   cols = (const int*)d_in[1];
    const float* vals = (const float*)d_in[2];
    const float* x    = (const float*)d_in[3];
    float*       out  = (float*)d_out;
    const int nnz = in_sizes[0];

    const size_t WF_BYTES = (size_t)GM * GK * 4;   // 64 MB fp32 W (later reused for xT)
    const size_t WB_BYTES = (size_t)GM * GK * 2;   // 32 MB bf16 W
    const size_t NEED = WF_BYTES + WB_BYTES;       // 96 MB

    if (ws_size >= NEED) {
        float*          Wf = (float*)d_ws;
        unsigned short* Wb = (unsigned short*)((char*)d_ws + WF_BYTES);
        unsigned short* xT = (unsigned short*)d_ws;  // reuses Wf region after convert_w

        hipMemsetAsync(Wf, 0, WF_BYTES, stream);
        scatter_dense<<<(nnz + 255) / 256, 256, 0, stream>>>(rows, cols, vals, Wf, nnz);
        convert_w<<<(GM * GK / 4) / 256, 256, 0, stream>>>(Wf, Wb);
        // Wf is dead now; overwrite its region with xT
        dim3 tg(GK / 64, GN / 64);
        transpose_x<<<tg, 256, 0, stream>>>(x, xT);
        dim3 gg(GN / 256, GM / 256);
        gemm256<<<gg, 512, 0, stream>>>(Wb, xT, out);
    } else {
        // fallback: CSR SpMM (round-1 path)
        int*   ws_i    = (int*)d_ws;
        int*   counts  = ws_i + WS_COUNTS;
        int*   offsets = ws_i + WS_OFFSETS;
        int*   cursor  = ws_i + WS_CURSOR;
        int*   cols_s  = ws_i + WS_HEADER;
        float* vals_s  = (float*)(ws_i + WS_HEADER + nnz);

        hipMemsetAsync(d_ws, 0, (size_t)WS_HEADER * sizeof(int), stream);
        const int nblk = (nnz + 255) / 256;
        hist_kernel<<<nblk, 256, 0, stream>>>(rows, counts, nnz);
        scan_kernel<<<1, 256, 0, stream>>>(counts, offsets);
        scatter_kernel<<<nblk, 256, 0, stream>>>(rows, cols, vals, offsets, cursor,
                                                 cols_s, vals_s, nnz);
        dim3 grid(OUT_F, NCOLS / 1024);
        spmm_kernel<<<grid, 256, 0, stream>>>(offsets, cols_s, vals_s, x, out);
    }
}

// Round 7
// 484.603 us; speedup vs baseline: 1.0964x; 1.0353x over previous
//
#include <hip/hip_runtime.h>

// Problem constants (match reference)
#define OUT_F 4096   // M
#define IN_F  4096   // K
#define NCOLS 8192   // N

#define GM OUT_F
#define GK IN_F
#define GN NCOLS

typedef __attribute__((ext_vector_type(8))) short short8;
typedef __attribute__((ext_vector_type(4))) float f32x4;

// ---------------------------------------------------------------------------
// helpers
// ---------------------------------------------------------------------------
__device__ inline unsigned short f2bf(float f) {
    union { float f; unsigned u; } c; c.f = f;
    unsigned u = c.u;
    u += 0x7fffu + ((u >> 16) & 1u);   // round-to-nearest-even
    return (unsigned short)(u >> 16);
}

__device__ inline void gll16(const void* g, void* l) {
    __builtin_amdgcn_global_load_lds(
        (const __attribute__((address_space(1))) unsigned int*)g,
        (__attribute__((address_space(3))) unsigned int*)l, 16, 0, 0);
}

// ---------------------------------------------------------------------------
// Densify path
// ---------------------------------------------------------------------------
__global__ void scatter_dense(const int* __restrict__ rows, const int* __restrict__ cols,
                              const float* __restrict__ vals, float* __restrict__ W, int nnz) {
    int i = blockIdx.x * blockDim.x + threadIdx.x;
    if (i < nnz) atomicAdd(&W[(size_t)rows[i] * IN_F + cols[i]], vals[i]);
}

__global__ void convert_w(const float* __restrict__ Wf, unsigned short* __restrict__ Wb) {
    int i = blockIdx.x * blockDim.x + threadIdx.x;  // over elems/4
    float4 v = ((const float4*)Wf)[i];
    ushort4 o;
    o.x = f2bf(v.x); o.y = f2bf(v.y); o.z = f2bf(v.z); o.w = f2bf(v.w);
    ((ushort4*)Wb)[i] = o;
}

// x [IN_F][NCOLS] f32 -> xT [NCOLS][IN_F] bf16, 64x64 tiles via LDS
__global__ __launch_bounds__(256) void transpose_x(const float* __restrict__ x,
                                                   unsigned short* __restrict__ xT) {
    __shared__ float tile[64][65];
    const int k0 = blockIdx.x * 64;   // x row block (K dim)
    const int n0 = blockIdx.y * 64;   // x col block (N dim)
    const int t = threadIdx.x;
    const int c4 = (t & 15) * 4;
    const int r0 = t >> 4;            // 0..15
    for (int p = 0; p < 4; ++p) {
        int r = r0 + p * 16;
        float4 v = *(const float4*)&x[(size_t)(k0 + r) * NCOLS + n0 + c4];
        tile[r][c4 + 0] = v.x; tile[r][c4 + 1] = v.y;
        tile[r][c4 + 2] = v.z; tile[r][c4 + 3] = v.w;
    }
    __syncthreads();
    const int n  = t >> 2;            // 0..63
    const int ks = (t & 3) * 16;      // 0,16,32,48
    unsigned w[8];
    for (int m = 0; m < 8; ++m) {
        unsigned short lo = f2bf(tile[ks + 2 * m + 0][n]);
        unsigned short hi = f2bf(tile[ks + 2 * m + 1][n]);
        w[m] = (unsigned)lo | ((unsigned)hi << 16);
    }
    uint4* dst = (uint4*)&xT[(size_t)(n0 + n) * GK + k0 + ks];
    dst[0] = make_uint4(w[0], w[1], w[2], w[3]);
    dst[1] = make_uint4(w[4], w[5], w[6], w[7]);
}

// ---------------------------------------------------------------------------
// GEMM: C[GM][GN] f32 = A(bf16 [GM][GK]) * B, with B given as BT bf16 [GN][GK].
// R7: rolling prefetch + sched_barrier pins (the overlap R4 wanted, fenced).
//   256x256 tile, 512 thr = 8 waves (2M x 4N), per-wave out 128x64.
//   LDS = 4 rotating slots of 32 KB (slot = A 256x32k | B 256x32k), BK=32/phase.
//   Phase p (slot e = p&3):
//     s_waitcnt vmcnt(4)      // retires stage@p-2 (tile p+1) -- counted, never 0
//     s_barrier               // seals slot (p+1)&3 cross-wave
//     sched_barrier(0)        // reads may not hoist above the seal
//     ds_read af2 (slot e, A rows 64..127 of wave half)        4x b128
//     ds_read bfN, afN (slot (e+1)&3, for phase p+1)           8x b128
//     STAGE tile p+3 -> slot (p+3)&3                           4x gll16
//     sched_barrier(0)        // reads/stage may not sink below (R4's failure)
//     setprio(1)
//     16 MFMA: acc[0..3] += afC x bfC   (regs read @p-1 -> lgkmcnt(12) wait)
//     16 MFMA: acc[4..7] += af2 x bfC   (af2 read @p    -> lgkmcnt(8) wait)
//     setprio(0)
//   Reads of phase p+1 retire UNDER phase p's MFMA window (LDS pipe ~1150 cyc
//   vs MFMA 1242 cyc/CU) -- breaking the serial read|barrier|MFMA structure
//   that capped R5/R6 at 51% MfmaUtil.
//   Ledger: RAW: tile p+1 resident by vmcnt(4)@p + barrier. WAR: stage@p
//   overwrites slot (p-1)&3; every wave's reads of tile p-1 completed into
//   registers before it reached barrier@p (lgkm waits precede its MFMA@p-1,
//   which precedes barrier@p); the stage issues after barrier@p. Slots touched
//   @p: read {e, e+1}, write {e+3} -- distinct mod 4.
//   Swizzle (R2-verified, 0 conflicts): 64B row = 4x16B slots; logical k-block
//   j of row r at slot j^((r>>1)&3); pre-swizzled global source (rule #21),
//   same involution on fragment reads.
//   wg swizzle: XCD-aware + N-banded (R5-verified: FETCH 625->199 MB).
// ---------------------------------------------------------------------------
__global__ __launch_bounds__(512, 2) void gemm256(const unsigned short* __restrict__ A,
                                                  const unsigned short* __restrict__ BT,
                                                  float* __restrict__ C) {
    __shared__ unsigned short lds[65536];   // 128 KiB = 4 slots x 16384 elems

    const int tid  = threadIdx.x;
    const int wave = tid >> 6;
    const int lane = tid & 63;

    // XCD-aware, N-banded bijective swizzle (nwg = 512)
    const int wg   = blockIdx.y * 32 + blockIdx.x;
    const int xcd  = wg & 7;
    const int ii   = wg >> 3;                       // 0..63
    const int m0   = ((((ii & 7) << 1) | (xcd & 1))) << 8;         // 16 M-tiles
    const int n0   = ((((ii >> 3) << 2) | ((xcd >> 1) & 3))) << 8; // 32 N-tiles, banded by 4
    const int wm = wave >> 2;          // 0..1  (M half of tile)
    const int wn = wave & 3;           // 0..3  (N quarter of tile)

    // ---- staging: chunk c = q*512 + tid; row = c>>2 (0..127 q=0, +128 q=1), slot = c&3.
    // fetch global k-block (c&3)^((row>>1)&3) so linear LDS slot holds swizzled data.
    const int r0s  = tid >> 2;                              // 0..127
    const int swz0 = ((tid & 3) ^ ((r0s >> 1) & 3)) << 3;   // elems
    const unsigned short* pA0 = A  + (size_t)(m0 + r0s) * GK + swz0;
    const unsigned short* pA1 = pA0 + (size_t)128 * GK;
    const unsigned short* pB0 = BT + (size_t)(n0 + r0s) * GK + swz0;
    const unsigned short* pB1 = pB0 + (size_t)128 * GK;

    // ---- fragment mapping (16x16x32): frow = lane&15, k-block jhi = lane>>4
    // A row r = wm*128 + H*64 + mi*16 + frow; B row r = wn*64 + nj*16 + frow.
    // All non-frow terms == 0 mod 8 -> (r>>1)&3 == (frow>>1)&3.
    const int frow  = lane & 15;
    const int ajb   = ((lane >> 4) ^ ((frow >> 1) & 3)) << 3;   // swizzled 8-elem block
    const int abase = (((wm << 7) + frow) << 5) + ajb;          // A elem offset in slot
    const int bbase = (((wn << 6) + frow) << 5) + 8192 + ajb;   // B elem offset in slot

    f32x4 acc[8][4] = {};

    // stage K-tile T_ into slot s_ (4 gll16/thread; dest wave-uniform + lane*16)
#define STAGE(T_, s_) do {                                              \
        const int ko_ = ((T_) & 127) << 5;                              \
        gll16(pA0 + ko_, &lds[(s_) * 16384 + (wave << 9)]);             \
        gll16(pA1 + ko_, &lds[(s_) * 16384 + 4096 + (wave << 9)]);      \
        gll16(pB0 + ko_, &lds[(s_) * 16384 + 8192 + (wave << 9)]);      \
        gll16(pB1 + ko_, &lds[(s_) * 16384 + 12288 + (wave << 9)]);     \
    } while (0)

    // prologue: tiles 0,1,2 -> slots 0,1,2; tile 0 resident; phase-0 frags read
    STAGE(0, 0); STAGE(1, 1); STAGE(2, 2);
    asm volatile("s_waitcnt vmcnt(8)");
    __builtin_amdgcn_s_barrier();

    short8 bfX[4], afX[4], bfY[4], afY[4];
    {
        const unsigned short* Ar0 = &lds[0];
#pragma unroll
        for (int nj = 0; nj < 4; ++nj) bfX[nj] = *(const short8*)&Ar0[bbase + nj * 512];
#pragma unroll
        for (int mi = 0; mi < 4; ++mi) afX[mi] = *(const short8*)&Ar0[abase + mi * 512];
    }

// one phase: e_ = p&3 compile-time; bfC/afC read @p-1, fills bfN/afN for p+1
#define PHASE(e_, bfC, afC, bfN, afN, jj) do {                                  \
        asm volatile("s_waitcnt vmcnt(4)");                                     \
        __builtin_amdgcn_s_barrier();                                           \
        __builtin_amdgcn_sched_barrier(0);                                      \
        const unsigned short* ArC = &lds[(e_) * 16384];                         \
        const unsigned short* ArN = &lds[(((e_) + 1) & 3) * 16384];             \
        short8 af2[4];                                                          \
        _Pragma("unroll")                                                       \
        for (int mi = 0; mi < 4; ++mi)                                          \
            af2[mi] = *(const short8*)&ArC[abase + 2048 + mi * 512];            \
        _Pragma("unroll")                                                       \
        for (int nj = 0; nj < 4; ++nj)                                          \
            bfN[nj] = *(const short8*)&ArN[bbase + nj * 512];                   \
        _Pragma("unroll")                                                       \
        for (int mi = 0; mi < 4; ++mi)                                          \
            afN[mi] = *(const short8*)&ArN[abase + mi * 512];                   \
        STAGE(4 * (jj) + (e_) + 3, ((e_) + 3) & 3);                             \
        __builtin_amdgcn_sched_barrier(0);                                      \
        __builtin_amdgcn_s_setprio(1);                                          \
        _Pragma("unroll")                                                       \
        for (int mi = 0; mi < 4; ++mi)                                          \
            _Pragma("unroll")                                                   \
            for (int nj = 0; nj < 4; ++nj)                                      \
                acc[mi][nj] = __builtin_amdgcn_mfma_f32_16x16x32_bf16(          \
                    afC[mi], bfC[nj], acc[mi][nj], 0, 0, 0);                    \
        _Pragma("unroll")                                                       \
        for (int mi = 0; mi < 4; ++mi)                                          \
            _Pragma("unroll")                                                   \
            for (int nj = 0; nj < 4; ++nj)                                      \
                acc[4 + mi][nj] = __builtin_amdgcn_mfma_f32_16x16x32_bf16(      \
                    af2[mi], bfC[nj], acc[4 + mi][nj], 0, 0, 0);                \
        __builtin_amdgcn_s_setprio(0);                                          \
    } while (0)

#pragma unroll 1
    for (int j = 0; j < GK / 128; ++j) {   // 32 iters x 4 phases (BK=32 each)
        PHASE(0, bfX, afX, bfY, afY, j);
        PHASE(1, bfY, afY, bfX, afX, j);
        PHASE(2, bfX, afX, bfY, afY, j);
        PHASE(3, bfY, afY, bfX, afX, j);
    }
#undef PHASE
#undef STAGE

    // epilogue: C/D layout col=lane&15, row=(lane>>4)*4+reg
    for (int mi = 0; mi < 8; ++mi) {
        const int r0w = m0 + wm * 128 + mi * 16 + (lane >> 4) * 4;
        for (int nj = 0; nj < 4; ++nj) {
            const int cc = n0 + wn * 64 + nj * 16 + frow;
            for (int r = 0; r < 4; ++r)
                C[(size_t)(r0w + r) * GN + cc] = acc[mi][nj][r];
        }
    }
}

// ---------------------------------------------------------------------------
// Fallback SpMM path (round-1 kernel) if workspace is too small for densify
// ---------------------------------------------------------------------------
#define WS_COUNTS  0
#define WS_OFFSETS 4097
#define WS_CURSOR  8194
#define WS_HEADER  12290

__global__ void hist_kernel(const int* __restrict__ rows, int* __restrict__ counts, int nnz) {
    int i = blockIdx.x * blockDim.x + threadIdx.x;
    if (i < nnz) atomicAdd(&counts[rows[i]], 1);
}

__global__ void scan_kernel(const int* __restrict__ counts, int* __restrict__ offsets) {
    __shared__ int lsum[256];
    int t = threadIdx.x;
    int base = t * 16;
    int local[16];
    int s = 0;
    for (int i = 0; i < 16; ++i) { local[i] = counts[base + i]; s += local[i]; }
    lsum[t] = s;
    __syncthreads();
    if (t == 0) {
        int acc = 0;
        for (int i = 0; i < 256; ++i) { int v = lsum[i]; lsum[i] = acc; acc += v; }
        offsets[OUT_F] = acc;
    }
    __syncthreads();
    int acc = lsum[t];
    for (int i = 0; i < 16; ++i) { offsets[base + i] = acc; acc += local[i]; }
}

__global__ void scatter_kernel(const int* __restrict__ rows, const int* __restrict__ cols,
                               const float* __restrict__ vals,
                               const int* __restrict__ offsets, int* __restrict__ cursor,
                               int* __restrict__ cols_s, float* __restrict__ vals_s, int nnz) {
    int i = blockIdx.x * blockDim.x + threadIdx.x;
    if (i < nnz) {
        int r = rows[i];
        int pos = offsets[r] + atomicAdd(&cursor[r], 1);
        cols_s[pos] = cols[i];
        vals_s[pos] = vals[i];
    }
}

__global__ __launch_bounds__(256) void spmm_kernel(const int* __restrict__ offsets,
                                                   const int* __restrict__ cols_s,
                                                   const float* __restrict__ vals_s,
                                                   const float* __restrict__ x,
                                                   float* __restrict__ out) {
    const int row  = blockIdx.x;
    const int col0 = blockIdx.y * 1024 + threadIdx.x * 4;
    const int k0 = offsets[row];
    const int k1 = offsets[row + 1];
    float4 acc = make_float4(0.f, 0.f, 0.f, 0.f);
    for (int k = k0; k < k1; ++k) {
        const int   c = cols_s[k];
        const float v = vals_s[k];
        const float4 xv = *reinterpret_cast<const float4*>(x + (size_t)c * NCOLS + col0);
        acc.x += v * xv.x;
        acc.y += v * xv.y;
        acc.z += v * xv.z;
        acc.w += v * xv.w;
    }
    *reinterpret_cast<float4*>(out + (size_t)row * NCOLS + col0) = acc;
}

// ---------------------------------------------------------------------------
extern "C" void kernel_launch(void* const* d_in, const int* in_sizes, int n_in,
                              void* d_out, int out_size, void* d_ws, size_t ws_size,
                              hipStream_t stream) {
    const int*   rows = (const int*)d_in[0];
    const int*   cols = (const int*)d_in[1];
    const float* vals = (const float*)d_in[2];
    const float* x    = (const float*)d_in[3];
    float*       out  = (float*)d_out;
    const int nnz = in_sizes[0];

    const size_t WF_BYTES = (size_t)GM * GK * 4;   // 64 MB fp32 W (later reused for xT)
    const size_t WB_BYTES = (size_t)GM * GK * 2;   // 32 MB bf16 W
    const size_t NEED = WF_BYTES + WB_BYTES;       // 96 MB

    if (ws_size >= NEED) {
        float*          Wf = (float*)d_ws;
        unsigned short* Wb = (unsigned short*)((char*)d_ws + WF_BYTES);
        unsigned short* xT = (unsigned short*)d_ws;  // reuses Wf region after convert_w

        hipMemsetAsync(Wf, 0, WF_BYTES, stream);
        scatter_dense<<<(nnz + 255) / 256, 256, 0, stream>>>(rows, cols, vals, Wf, nnz);
        convert_w<<<(GM * GK / 4) / 256, 256, 0, stream>>>(Wf, Wb);
        // Wf is dead now; overwrite its region with xT
        dim3 tg(GK / 64, GN / 64);
        transpose_x<<<tg, 256, 0, stream>>>(x, xT);
        dim3 gg(GN / 256, GM / 256);
        gemm256<<<gg, 512, 0, stream>>>(Wb, xT, out);
    } else {
        // fallback: CSR SpMM (round-1 path)
        int*   ws_i    = (int*)d_ws;
        int*   counts  = ws_i + WS_COUNTS;
        int*   offsets = ws_i + WS_OFFSETS;
        int*   cursor  = ws_i + WS_CURSOR;
        int*   cols_s  = ws_i + WS_HEADER;
        float* vals_s  = (float*)(ws_i + WS_HEADER + nnz);

        hipMemsetAsync(d_ws, 0, (size_t)WS_HEADER * sizeof(int), stream);
        const int nblk = (nnz + 255) / 256;
        hist_kernel<<<nblk, 256, 0, stream>>>(rows, counts, nnz);
        scan_kernel<<<1, 256, 0, stream>>>(counts, offsets);
        scatter_kernel<<<nblk, 256, 0, stream>>>(rows, cols, vals, offsets, cursor,
                                                 cols_s, vals_s, nnz);
        dim3 grid(OUT_F, NCOLS / 1024);
        spmm_kernel<<<grid, 256, 0, stream>>>(offsets, cols_s, vals_s, x, out);
    }
}